// Round 2
// baseline (1207.748 us; speedup 1.0000x reference)
//
#include <hip/hip_runtime.h>

// ---------------------------------------------------------------------------
// SpectralNet loss pipeline on MI355X.
//   pass1: y1 = MLP(x1)/d1 -> gram -> cholesky -> operator = inv(L)^T*sqrt(N)
//   pass2: y  = (MLP(x2) @ operator)/d2 -> loss = sum_e de*(d2[i]+d2[j])/N
// GEMMs: bf16 MFMA 16x16x32, fp32 accum. Weights pre-transposed to [out][in].
// MLP is chunked over rows so activation scratch fits ws_size (chunk picked
// deterministically from ws_size).
// ---------------------------------------------------------------------------

#define NPTS  65536
#define KNN   16
#define INDIM 128
#define HID   1024
#define HID2  512
#define ODIM  32

typedef unsigned short u16;
typedef __attribute__((ext_vector_type(8))) short bf16x8;
typedef __attribute__((ext_vector_type(4))) float f32x4;

__device__ __forceinline__ u16 f2bf(float v) {
    union { float f; unsigned u; } x; x.f = v;
    unsigned r = x.u + 0x7fffu + ((x.u >> 16) & 1u);   // round-to-nearest-even
    return (u16)(r >> 16);
}

// ---------------- conversion / transpose ----------------
__global__ void cvt_bf16_k(const float* __restrict__ in, u16* __restrict__ out, int n4) {
    int i = blockIdx.x * blockDim.x + threadIdx.x;
    if (i >= n4) return;
    float4 v = reinterpret_cast<const float4*>(in)[i];
    unsigned lo = (unsigned)f2bf(v.x) | ((unsigned)f2bf(v.y) << 16);
    unsigned hi = (unsigned)f2bf(v.z) | ((unsigned)f2bf(v.w) << 16);
    reinterpret_cast<uint2*>(out)[i] = make_uint2(lo, hi);
}

// W [rows][cols] f32 -> Wt [cols][rows] bf16   (write-coalesced)
__global__ void trans_bf16_k(const float* __restrict__ W, u16* __restrict__ Wt,
                             int rows, int cols) {
    int idx = blockIdx.x * blockDim.x + threadIdx.x;
    if (idx >= rows * cols) return;
    int o = idx / rows, i = idx - o * rows;
    Wt[idx] = f2bf(W[(size_t)i * cols + o]);
}

// ---------------- degree ----------------
__global__ void degree_k(const float* __restrict__ dists, const int* __restrict__ nn,
                         float* __restrict__ d) {
    int i = blockIdx.x * blockDim.x + threadIdx.x;
    if (i >= NPTS) return;
    float w[KNN];
    float s = 0.f;
    const float4* dr = reinterpret_cast<const float4*>(dists + (size_t)i * KNN);
    float4 a = dr[0], b = dr[1], c = dr[2], e = dr[3];
    float buf[KNN] = {a.x,a.y,a.z,a.w,b.x,b.y,b.z,b.w,c.x,c.y,c.z,c.w,e.x,e.y,e.z,e.w};
    #pragma unroll
    for (int k = 0; k < KNN; ++k) s += buf[k];
    float sigma = s * (1.f / KNN);
    float inv2s2 = 1.f / (2.f * sigma * sigma);
    float rs = 0.f;
    #pragma unroll
    for (int k = 0; k < KNN; ++k) { w[k] = __expf(-buf[k] * buf[k] * inv2s2); rs += w[k]; }
    atomicAdd(&d[i], 0.5f * rs);
    #pragma unroll
    for (int k = 0; k < KNN; ++k) atomicAdd(&d[nn[(size_t)i * KNN + k]], 0.5f * w[k]);
}

// ---------------- GEMM: C = relu(A @ Bt^T + bias), bf16 in/out --------------
// A [M][Kd] bf16, Bt [Ncols][Kd] bf16, C [M][Ncols] bf16. 128x128 tile, BK=64.
#define LDSS 72   // 64 + 8 pad (row stride 144B: 16B-aligned, 2-way banks max)

template <bool RELU>
__global__ __launch_bounds__(256) void gemm_bt_k(
    const u16* __restrict__ A, const u16* __restrict__ Bt,
    const float* __restrict__ bias, u16* __restrict__ C,
    int M, int Ncols, int Kd)
{
    __shared__ __attribute__((aligned(16))) u16 As[128 * LDSS];
    __shared__ __attribute__((aligned(16))) u16 Bs[128 * LDSS];
    const int tid  = threadIdx.x;
    const int lane = tid & 63;
    const int wave = tid >> 6;
    const int wr   = wave >> 1;        // 0..1
    const int wc   = wave & 1;         // 0..1
    const int l15  = lane & 15;
    const int kq   = lane >> 4;        // 0..3
    const int m0   = blockIdx.y * 128;
    const int n0   = blockIdx.x * 128;

    f32x4 acc[4][4] = {};

    for (int kt = 0; kt < Kd; kt += 64) {
        #pragma unroll
        for (int j = 0; j < 4; ++j) {
            int cch = tid + j * 256;          // 0..1023
            int row = cch >> 3;               // 0..127
            int ko  = (cch & 7) * 8;          // 0..56
            *reinterpret_cast<uint4*>(&As[row * LDSS + ko]) =
                *reinterpret_cast<const uint4*>(A + (size_t)(m0 + row) * Kd + kt + ko);
            *reinterpret_cast<uint4*>(&Bs[row * LDSS + ko]) =
                *reinterpret_cast<const uint4*>(Bt + (size_t)(n0 + row) * Kd + kt + ko);
        }
        __syncthreads();
        #pragma unroll
        for (int ks = 0; ks < 2; ++ks) {
            bf16x8 af[4], bfr[4];
            #pragma unroll
            for (int mi = 0; mi < 4; ++mi)
                af[mi] = *reinterpret_cast<const bf16x8*>(
                    &As[(wr * 64 + mi * 16 + l15) * LDSS + ks * 32 + kq * 8]);
            #pragma unroll
            for (int ni = 0; ni < 4; ++ni)
                bfr[ni] = *reinterpret_cast<const bf16x8*>(
                    &Bs[(wc * 64 + ni * 16 + l15) * LDSS + ks * 32 + kq * 8]);
            #pragma unroll
            for (int mi = 0; mi < 4; ++mi)
                #pragma unroll
                for (int ni = 0; ni < 4; ++ni)
                    acc[mi][ni] = __builtin_amdgcn_mfma_f32_16x16x32_bf16(
                        af[mi], bfr[ni], acc[mi][ni], 0, 0, 0);
        }
        __syncthreads();
    }

    #pragma unroll
    for (int mi = 0; mi < 4; ++mi) {
        #pragma unroll
        for (int ni = 0; ni < 4; ++ni) {
            int col = n0 + wc * 64 + ni * 16 + l15;
            float bv = bias[col];
            #pragma unroll
            for (int r = 0; r < 4; ++r) {
                int row = m0 + wr * 64 + mi * 16 + kq * 4 + r;
                float v = acc[mi][ni][r] + bv;
                if (RELU) v = v > 0.f ? v : 0.f;
                C[(size_t)row * Ncols + col] = f2bf(v);
            }
        }
    }
}

// ---------------- layer 4: Y[M][32] f32 = A[M][512] @ W4t^T + b4 (/ dscale) --
__global__ __launch_bounds__(256) void layer4_k(
    const u16* __restrict__ A, const u16* __restrict__ Bt,
    const float* __restrict__ bias, const float* __restrict__ dscale,
    float* __restrict__ Y, int M)
{
    __shared__ __attribute__((aligned(16))) u16 Bs[32 * 520];
    int tid = threadIdx.x;
    #pragma unroll
    for (int j = 0; j < 8; ++j) {
        int cch = tid + j * 256;          // 0..2047
        int row = cch >> 6;               // 0..31
        int ko  = (cch & 63) * 8;         // 0..504
        *reinterpret_cast<uint4*>(&Bs[row * 520 + ko]) =
            *reinterpret_cast<const uint4*>(Bt + (size_t)row * 512 + ko);
    }
    __syncthreads();
    int lane = tid & 63, wave = tid >> 6;
    int l15 = lane & 15, kq = lane >> 4;
    int rowb = blockIdx.x * 64 + wave * 16;
    f32x4 acc[2] = {};
    const u16* Arow = A + (size_t)(rowb + l15) * 512;
    #pragma unroll
    for (int ks = 0; ks < 16; ++ks) {
        bf16x8 a = *reinterpret_cast<const bf16x8*>(Arow + ks * 32 + kq * 8);
        #pragma unroll
        for (int ni = 0; ni < 2; ++ni) {
            bf16x8 b = *reinterpret_cast<const bf16x8*>(&Bs[(ni * 16 + l15) * 520 + ks * 32 + kq * 8]);
            acc[ni] = __builtin_amdgcn_mfma_f32_16x16x32_bf16(a, b, acc[ni], 0, 0, 0);
        }
    }
    #pragma unroll
    for (int ni = 0; ni < 2; ++ni) {
        int col = ni * 16 + l15;
        float bv = bias[col];
        #pragma unroll
        for (int r = 0; r < 4; ++r) {
            int rr = rowb + kq * 4 + r;
            float v = acc[ni][r] + bv;
            if (dscale) v /= dscale[rr];
            Y[(size_t)rr * 32 + col] = v;
        }
    }
}

// ---------------- gram: G[32][32] += sum_i y_i y_i^T ----------------
__global__ __launch_bounds__(256) void gram_k(const float* __restrict__ Y,
                                              float* __restrict__ G) {
    __shared__ float ys[8][32];
    const int ROWS = NPTS / 256;            // grid must be 256 blocks
    int base = blockIdx.x * ROWS;
    int tid = threadIdx.x;
    int r = tid >> 3, c0 = (tid & 7) * 4;
    float a0 = 0, a1 = 0, a2 = 0, a3 = 0;
    for (int i0 = 0; i0 < ROWS; i0 += 8) {
        ys[tid >> 5][tid & 31] = Y[(size_t)(base + i0 + (tid >> 5)) * 32 + (tid & 31)];
        __syncthreads();
        #pragma unroll
        for (int q = 0; q < 8; ++q) {
            float yr = ys[q][r];
            a0 += yr * ys[q][c0];     a1 += yr * ys[q][c0 + 1];
            a2 += yr * ys[q][c0 + 2]; a3 += yr * ys[q][c0 + 3];
        }
        __syncthreads();
    }
    atomicAdd(&G[r * 32 + c0], a0);     atomicAdd(&G[r * 32 + c0 + 1], a1);
    atomicAdd(&G[r * 32 + c0 + 2], a2); atomicAdd(&G[r * 32 + c0 + 3], a3);
}

// ---------------- cholesky + triangular inverse (fp64, 1 block) -------------
__global__ void chol_oper_k(const float* __restrict__ G, float* __restrict__ oper) {
    __shared__ double Ad[32][33];
    __shared__ double Xs[32][33];
    int t = threadIdx.x;
    if (t < 32)
        for (int j = 0; j < 32; ++j)
            Ad[t][j] = (double)G[t * 32 + j] + (t == j ? 1e-7 : 0.0);
    __syncthreads();
    for (int k = 0; k < 32; ++k) {
        if (t == 0) Ad[k][k] = sqrt(Ad[k][k]);
        __syncthreads();
        if (t > k && t < 32) Ad[t][k] /= Ad[k][k];
        __syncthreads();
        if (t > k && t < 32)
            for (int j = k + 1; j <= t; ++j) Ad[t][j] -= Ad[t][k] * Ad[j][k];
        __syncthreads();
    }
    // thread t solves L x = e_t  ->  x = column t of inv(L); oper[t][j] = x[j]*256
    if (t < 32) {
        Xs[t][t] = 1.0 / Ad[t][t];
        for (int r = t + 1; r < 32; ++r) {
            double s = 0.0;
            for (int j = t; j < r; ++j) s += Ad[r][j] * Xs[j][t];
            Xs[r][t] = -s / Ad[r][r];
        }
        for (int j = 0; j < t; ++j)  oper[t * 32 + j] = 0.f;
        for (int j = t; j < 32; ++j) oper[t * 32 + j] = (float)(Xs[j][t] * 256.0);
    }
}

// ---------------- y = (Yraw @ oper) / d2 ----------------
__global__ __launch_bounds__(256) void apply_oper_k(
    const float* __restrict__ Yr, const float* __restrict__ oper,
    const float* __restrict__ d2, float* __restrict__ Yo) {
    __shared__ float op[1024];
    int tid = threadIdx.x;
    #pragma unroll
    for (int j = tid; j < 1024; j += 256) op[j] = oper[j];
    __syncthreads();
    int idx = blockIdx.x * 256 + tid;          // over NPTS*32
    int i = idx >> 5, j = idx & 31;
    const float* row = Yr + (size_t)i * 32;
    float s = 0.f;
    #pragma unroll
    for (int q = 0; q < 32; ++q) s += row[q] * op[q * 32 + j];
    Yo[idx] = s / d2[i];
}

// ---------------- loss = sum_e ||y_i - y_j||^2 * (d2[i]+d2[j]) --------------
__global__ __launch_bounds__(256) void loss_k(
    const float* __restrict__ Y, const int* __restrict__ nn,
    const float* __restrict__ d2, double* __restrict__ acc) {
    int e = blockIdx.x * 256 + threadIdx.x;    // over NPTS*KNN
    double local = 0.0;
    if (e < NPTS * KNN) {
        int i = e >> 4;
        int j = nn[e];
        const float4* yi = reinterpret_cast<const float4*>(Y + (size_t)i * 32);
        const float4* yj = reinterpret_cast<const float4*>(Y + (size_t)j * 32);
        float s = 0.f;
        #pragma unroll
        for (int q = 0; q < 8; ++q) {
            float4 a = yi[q], b = yj[q];
            float dx = a.x - b.x, dy = a.y - b.y, dz = a.z - b.z, dw = a.w - b.w;
            s += dx * dx + dy * dy + dz * dz + dw * dw;
        }
        local = (double)s * ((double)d2[i] + (double)d2[j]);
    }
    #pragma unroll
    for (int off = 32; off > 0; off >>= 1) local += __shfl_down(local, off);
    if ((threadIdx.x & 63) == 0) atomicAdd(acc, local);
}

__global__ void finalize_k(const double* __restrict__ acc, float* __restrict__ out) {
    out[0] = (float)(acc[0] / (double)NPTS);
}

// ---------------------------------------------------------------------------
extern "C" void kernel_launch(void* const* d_in, const int* in_sizes, int n_in,
                              void* d_out, int out_size, void* d_ws, size_t ws_size,
                              hipStream_t stream) {
    const float* x1     = (const float*)d_in[0];
    const float* x2     = (const float*)d_in[1];
    const float* dists1 = (const float*)d_in[2];
    const int*   nn1    = (const int*)  d_in[3];
    const float* dists2 = (const float*)d_in[4];
    const int*   nn2    = (const int*)  d_in[5];
    const float* W1 = (const float*)d_in[6];  const float* b1 = (const float*)d_in[7];
    const float* W2 = (const float*)d_in[8];  const float* b2 = (const float*)d_in[9];
    const float* W3 = (const float*)d_in[10]; const float* b3 = (const float*)d_in[11];
    const float* W4 = (const float*)d_in[12]; const float* b4 = (const float*)d_in[13];

    char* ws = (char*)d_ws;
    size_t off = 0;
    auto alloc = [&](size_t bytes) { char* p = ws + off; off += (bytes + 255) & ~(size_t)255; return p; };
    u16*    xb   = (u16*)   alloc((size_t)NPTS * INDIM * 2);
    float*  yraw = (float*) alloc((size_t)NPTS * ODIM * 4);
    float*  yop  = (float*) alloc((size_t)NPTS * ODIM * 4);
    u16*    W1t  = (u16*)   alloc((size_t)HID * INDIM * 2);
    u16*    W2t  = (u16*)   alloc((size_t)HID * HID * 2);
    u16*    W3t  = (u16*)   alloc((size_t)HID2 * HID * 2);
    u16*    W4t  = (u16*)   alloc((size_t)ODIM * HID2 * 2);
    float*  d1   = (float*) alloc((size_t)NPTS * 4);
    float*  d2   = (float*) alloc((size_t)NPTS * 4);
    float*  gram = (float*) alloc(32 * 32 * 4);
    float*  oper = (float*) alloc(32 * 32 * 4);
    double* acc  = (double*)alloc(256);
    size_t fixed = off;
    (void)in_sizes; (void)n_in; (void)out_size;

    // Chunk the MLP so 2 x chunk x 1024 bf16 activation buffers fit ws_size.
    int chunk = 2048;
    for (int c = NPTS; c >= 2048; c >>= 1)
        if (fixed + (size_t)c * 1024 * 2 * 2 + 512 <= ws_size) { chunk = c; break; }
    u16* cb1 = (u16*)alloc((size_t)chunk * HID * 2);
    u16* cb2 = (u16*)alloc((size_t)chunk * HID * 2);

    // weight transposes + zero-init
    trans_bf16_k<<<(INDIM * HID + 255) / 256, 256, 0, stream>>>(W1, W1t, INDIM, HID);
    trans_bf16_k<<<(HID * HID + 255) / 256, 256, 0, stream>>>(W2, W2t, HID, HID);
    trans_bf16_k<<<(HID * HID2 + 255) / 256, 256, 0, stream>>>(W3, W3t, HID, HID2);
    trans_bf16_k<<<(HID2 * ODIM + 255) / 256, 256, 0, stream>>>(W4, W4t, HID2, ODIM);
    hipMemsetAsync(d1, 0, (size_t)NPTS * 4, stream);
    hipMemsetAsync(d2, 0, (size_t)NPTS * 4, stream);
    hipMemsetAsync(gram, 0, 32 * 32 * 4, stream);
    hipMemsetAsync(acc, 0, 8, stream);

    degree_k<<<NPTS / 256, 256, 0, stream>>>(dists1, nn1, d1);
    degree_k<<<NPTS / 256, 256, 0, stream>>>(dists2, nn2, d2);

    dim3 gL12(HID / 128, chunk / 128), gL3(HID2 / 128, chunk / 128);

    for (int pass = 0; pass < 2; ++pass) {
        const float* x = pass == 0 ? x1 : x2;
        cvt_bf16_k<<<(NPTS * INDIM / 4 + 255) / 256, 256, 0, stream>>>(x, xb, NPTS * INDIM / 4);
        for (int s0 = 0; s0 < NPTS; s0 += chunk) {
            const u16* Ain = xb + (size_t)s0 * INDIM;
            gemm_bt_k<true><<<gL12, 256, 0, stream>>>(Ain, W1t, b1, cb1, chunk, HID, INDIM);
            gemm_bt_k<true><<<gL12, 256, 0, stream>>>(cb1, W2t, b2, cb2, chunk, HID, HID);
            gemm_bt_k<true><<<gL3, 256, 0, stream>>>(cb2, W3t, b3, cb1, chunk, HID2, HID);
            layer4_k<<<chunk / 64, 256, 0, stream>>>(
                cb1, W4t, b4, pass == 0 ? d1 + s0 : nullptr,
                yraw + (size_t)s0 * ODIM, chunk);
        }
        if (pass == 0) {
            gram_k<<<256, 256, 0, stream>>>(yraw, gram);
            chol_oper_k<<<1, 64, 0, stream>>>(gram, oper);
        } else {
            apply_oper_k<<<NPTS * ODIM / 256, 256, 0, stream>>>(yraw, oper, d2, yop);
            loss_k<<<NPTS * KNN / 256, 256, 0, stream>>>(yop, nn2, d2, acc);
            finalize_k<<<1, 1, 0, stream>>>(acc, (float*)d_out);
        }
    }
}

// Round 3
// 1083.820 us; speedup vs baseline: 1.1143x; 1.1143x over previous
//
#include <hip/hip_runtime.h>

// ---------------------------------------------------------------------------
// SpectralNet loss pipeline on MI355X.
//   pass1: y1 = MLP(x1)/d1 -> gram -> cholesky -> operator = inv(L)^T*sqrt(N)
//   pass2: y  = (MLP(x2) @ operator)/d2 -> loss = sum_e de*(d2[i]+d2[j])/N
// GEMMs: bf16 MFMA 16x16x32, fp32 accum, global_load_lds(16B) staging,
// linear LDS (m97 structure). Loss: atomic-free two-stage reduction.
// ---------------------------------------------------------------------------

#define NPTS  65536
#define KNN   16
#define INDIM 128
#define HID   1024
#define HID2  512
#define ODIM  32

typedef unsigned short u16;
typedef unsigned int   u32;
typedef __attribute__((ext_vector_type(8))) short bf16x8;
typedef __attribute__((ext_vector_type(4))) float f32x4;

__device__ __forceinline__ u16 f2bf(float v) {
    union { float f; unsigned u; } x; x.f = v;
    unsigned r = x.u + 0x7fffu + ((x.u >> 16) & 1u);   // round-to-nearest-even
    return (u16)(r >> 16);
}

__device__ __forceinline__ void gload_lds16(const u16* g, u16* l) {
    __builtin_amdgcn_global_load_lds(
        (const __attribute__((address_space(1))) u32*)g,
        (__attribute__((address_space(3))) u32*)l, 16, 0, 0);
}

// ---------------- conversion / transpose ----------------
__global__ void cvt_bf16_k(const float* __restrict__ in, u16* __restrict__ out, int n4) {
    int i = blockIdx.x * blockDim.x + threadIdx.x;
    if (i >= n4) return;
    float4 v = reinterpret_cast<const float4*>(in)[i];
    unsigned lo = (unsigned)f2bf(v.x) | ((unsigned)f2bf(v.y) << 16);
    unsigned hi = (unsigned)f2bf(v.z) | ((unsigned)f2bf(v.w) << 16);
    reinterpret_cast<uint2*>(out)[i] = make_uint2(lo, hi);
}

// W [rows][cols] f32 -> Wt [cols][rows] bf16   (write-coalesced)
__global__ void trans_bf16_k(const float* __restrict__ W, u16* __restrict__ Wt,
                             int rows, int cols) {
    int idx = blockIdx.x * blockDim.x + threadIdx.x;
    if (idx >= rows * cols) return;
    int o = idx / rows, i = idx - o * rows;
    Wt[idx] = f2bf(W[(size_t)i * cols + o]);
}

// ---------------- degree ----------------
__global__ void degree_k(const float* __restrict__ dists, const int* __restrict__ nn,
                         float* __restrict__ d) {
    int i = blockIdx.x * blockDim.x + threadIdx.x;
    if (i >= NPTS) return;
    float w[KNN];
    float s = 0.f;
    const float4* dr = reinterpret_cast<const float4*>(dists + (size_t)i * KNN);
    float4 a = dr[0], b = dr[1], c = dr[2], e = dr[3];
    float buf[KNN] = {a.x,a.y,a.z,a.w,b.x,b.y,b.z,b.w,c.x,c.y,c.z,c.w,e.x,e.y,e.z,e.w};
    #pragma unroll
    for (int k = 0; k < KNN; ++k) s += buf[k];
    float sigma = s * (1.f / KNN);
    float inv2s2 = 1.f / (2.f * sigma * sigma);
    float rs = 0.f;
    #pragma unroll
    for (int k = 0; k < KNN; ++k) { w[k] = __expf(-buf[k] * buf[k] * inv2s2); rs += w[k]; }
    atomicAdd(&d[i], 0.5f * rs);
    #pragma unroll
    for (int k = 0; k < KNN; ++k) atomicAdd(&d[nn[(size_t)i * KNN + k]], 0.5f * w[k]);
}

// ---------------- GEMM: C = relu(A @ Bt^T + bias), bf16 in/out --------------
// A [M][Kd] bf16, Bt [Ncols][Kd] bf16, C [M][Ncols] bf16.
// 128x128 tile, BK=64, linear LDS [128][64], global_load_lds 16B staging.
template <bool RELU>
__global__ __launch_bounds__(256) void gemm_bt_k(
    const u16* __restrict__ A, const u16* __restrict__ Bt,
    const float* __restrict__ bias, u16* __restrict__ C,
    int M, int Ncols, int Kd)
{
    __shared__ __attribute__((aligned(16))) u16 As[128 * 64];
    __shared__ __attribute__((aligned(16))) u16 Bs[128 * 64];
    const int tid  = threadIdx.x;
    const int lane = tid & 63;
    const int wave = tid >> 6;
    const int wr   = wave >> 1;        // 0..1
    const int wc   = wave & 1;         // 0..1
    const int l15  = lane & 15;
    const int kq   = lane >> 4;        // 0..3
    const int m0   = blockIdx.y * 128;
    const int n0   = blockIdx.x * 128;

    // staging geometry: segment = 1 KiB = 8 rows x 64 cols (bf16).
    // lane l covers row seg*8 + (l>>3), elems (l&7)*8..+7 -> LDS base+16B*l.
    const int srow = lane >> 3;          // 0..7
    const int scol = (lane & 7) * 8;     // 0..56

    f32x4 acc[4][4] = {};

    for (int kt = 0; kt < Kd; kt += 64) {
        #pragma unroll
        for (int j = 0; j < 4; ++j) {
            int seg = wave * 4 + j;                  // 0..15
            int row = seg * 8 + srow;                // 0..127
            gload_lds16(A  + (size_t)(m0 + row) * Kd + kt + scol, &As[seg * 512]);
            gload_lds16(Bt + (size_t)(n0 + row) * Kd + kt + scol, &Bs[seg * 512]);
        }
        __syncthreads();
        #pragma unroll
        for (int ks = 0; ks < 2; ++ks) {
            bf16x8 af[4], bfr[4];
            #pragma unroll
            for (int mi = 0; mi < 4; ++mi)
                af[mi] = *reinterpret_cast<const bf16x8*>(
                    &As[(wr * 64 + mi * 16 + l15) * 64 + ks * 32 + kq * 8]);
            #pragma unroll
            for (int ni = 0; ni < 4; ++ni)
                bfr[ni] = *reinterpret_cast<const bf16x8*>(
                    &Bs[(wc * 64 + ni * 16 + l15) * 64 + ks * 32 + kq * 8]);
            #pragma unroll
            for (int mi = 0; mi < 4; ++mi)
                #pragma unroll
                for (int ni = 0; ni < 4; ++ni)
                    acc[mi][ni] = __builtin_amdgcn_mfma_f32_16x16x32_bf16(
                        af[mi], bfr[ni], acc[mi][ni], 0, 0, 0);
        }
        __syncthreads();
    }

    #pragma unroll
    for (int mi = 0; mi < 4; ++mi) {
        #pragma unroll
        for (int ni = 0; ni < 4; ++ni) {
            int col = n0 + wc * 64 + ni * 16 + l15;
            float bv = bias[col];
            #pragma unroll
            for (int r = 0; r < 4; ++r) {
                int row = m0 + wr * 64 + mi * 16 + kq * 4 + r;
                float v = acc[mi][ni][r] + bv;
                if (RELU) v = v > 0.f ? v : 0.f;
                C[(size_t)row * Ncols + col] = f2bf(v);
            }
        }
    }
}

// ---------------- layer 4: Y[M][32] f32 = A[M][512] @ W4t^T + b4 (/ dscale) --
__global__ __launch_bounds__(256) void layer4_k(
    const u16* __restrict__ A, const u16* __restrict__ Bt,
    const float* __restrict__ bias, const float* __restrict__ dscale,
    float* __restrict__ Y, int M)
{
    __shared__ __attribute__((aligned(16))) u16 Bs[32 * 520];
    int tid = threadIdx.x;
    #pragma unroll
    for (int j = 0; j < 8; ++j) {
        int cch = tid + j * 256;          // 0..2047
        int row = cch >> 6;               // 0..31
        int ko  = (cch & 63) * 8;         // 0..504
        *reinterpret_cast<uint4*>(&Bs[row * 520 + ko]) =
            *reinterpret_cast<const uint4*>(Bt + (size_t)row * 512 + ko);
    }
    __syncthreads();
    int lane = tid & 63, wave = tid >> 6;
    int l15 = lane & 15, kq = lane >> 4;
    int rowb = blockIdx.x * 64 + wave * 16;
    f32x4 acc[2] = {};
    const u16* Arow = A + (size_t)(rowb + l15) * 512;
    #pragma unroll
    for (int ks = 0; ks < 16; ++ks) {
        bf16x8 a = *reinterpret_cast<const bf16x8*>(Arow + ks * 32 + kq * 8);
        #pragma unroll
        for (int ni = 0; ni < 2; ++ni) {
            bf16x8 b = *reinterpret_cast<const bf16x8*>(&Bs[(ni * 16 + l15) * 520 + ks * 32 + kq * 8]);
            acc[ni] = __builtin_amdgcn_mfma_f32_16x16x32_bf16(a, b, acc[ni], 0, 0, 0);
        }
    }
    #pragma unroll
    for (int ni = 0; ni < 2; ++ni) {
        int col = ni * 16 + l15;
        float bv = bias[col];
        #pragma unroll
        for (int r = 0; r < 4; ++r) {
            int rr = rowb + kq * 4 + r;
            float v = acc[ni][r] + bv;
            if (dscale) v /= dscale[rr];
            Y[(size_t)rr * 32 + col] = v;
        }
    }
}

// ---------------- gram: G[32][32] += sum_i y_i y_i^T ----------------
__global__ __launch_bounds__(256) void gram_k(const float* __restrict__ Y,
                                              float* __restrict__ G) {
    __shared__ float ys[8][32];
    const int ROWS = NPTS / 256;            // grid must be 256 blocks
    int base = blockIdx.x * ROWS;
    int tid = threadIdx.x;
    int r = tid >> 3, c0 = (tid & 7) * 4;
    float a0 = 0, a1 = 0, a2 = 0, a3 = 0;
    for (int i0 = 0; i0 < ROWS; i0 += 8) {
        ys[tid >> 5][tid & 31] = Y[(size_t)(base + i0 + (tid >> 5)) * 32 + (tid & 31)];
        __syncthreads();
        #pragma unroll
        for (int q = 0; q < 8; ++q) {
            float yr = ys[q][r];
            a0 += yr * ys[q][c0];     a1 += yr * ys[q][c0 + 1];
            a2 += yr * ys[q][c0 + 2]; a3 += yr * ys[q][c0 + 3];
        }
        __syncthreads();
    }
    atomicAdd(&G[r * 32 + c0], a0);     atomicAdd(&G[r * 32 + c0 + 1], a1);
    atomicAdd(&G[r * 32 + c0 + 2], a2); atomicAdd(&G[r * 32 + c0 + 3], a3);
}

// ---------------- cholesky + triangular inverse (fp64, 1 block) -------------
__global__ void chol_oper_k(const float* __restrict__ G, float* __restrict__ oper) {
    __shared__ double Ad[32][33];
    __shared__ double Xs[32][33];
    int t = threadIdx.x;
    if (t < 32)
        for (int j = 0; j < 32; ++j)
            Ad[t][j] = (double)G[t * 32 + j] + (t == j ? 1e-7 : 0.0);
    __syncthreads();
    for (int k = 0; k < 32; ++k) {
        if (t == 0) Ad[k][k] = sqrt(Ad[k][k]);
        __syncthreads();
        if (t > k && t < 32) Ad[t][k] /= Ad[k][k];
        __syncthreads();
        if (t > k && t < 32)
            for (int j = k + 1; j <= t; ++j) Ad[t][j] -= Ad[t][k] * Ad[j][k];
        __syncthreads();
    }
    // thread t solves L x = e_t  ->  x = column t of inv(L); oper[t][j] = x[j]*256
    if (t < 32) {
        Xs[t][t] = 1.0 / Ad[t][t];
        for (int r = t + 1; r < 32; ++r) {
            double s = 0.0;
            for (int j = t; j < r; ++j) s += Ad[r][j] * Xs[j][t];
            Xs[r][t] = -s / Ad[r][r];
        }
        for (int j = 0; j < t; ++j)  oper[t * 32 + j] = 0.f;
        for (int j = t; j < 32; ++j) oper[t * 32 + j] = (float)(Xs[j][t] * 256.0);
    }
}

// ---------------- y = (Yraw @ oper) / d2 ----------------
__global__ __launch_bounds__(256) void apply_oper_k(
    const float* __restrict__ Yr, const float* __restrict__ oper,
    const float* __restrict__ d2, float* __restrict__ Yo) {
    __shared__ float op[1024];
    int tid = threadIdx.x;
    #pragma unroll
    for (int j = tid; j < 1024; j += 256) op[j] = oper[j];
    __syncthreads();
    int idx = blockIdx.x * 256 + tid;          // over NPTS*32
    int i = idx >> 5, j = idx & 31;
    const float* row = Yr + (size_t)i * 32;
    float s = 0.f;
    #pragma unroll
    for (int q = 0; q < 32; ++q) s += row[q] * op[q * 32 + j];
    Yo[idx] = s / d2[i];
}

// ---- loss partials: part[b] = sum_block ||y_i - y_j||^2 * (d2[i]+d2[j]) ----
__global__ __launch_bounds__(256) void loss_k(
    const float* __restrict__ Y, const int* __restrict__ nn,
    const float* __restrict__ d2, double* __restrict__ part) {
    int e = blockIdx.x * 256 + threadIdx.x;    // over NPTS*KNN
    int i = e >> 4;
    int j = nn[e];
    const float4* yi = reinterpret_cast<const float4*>(Y + (size_t)i * 32);
    const float4* yj = reinterpret_cast<const float4*>(Y + (size_t)j * 32);
    float s = 0.f;
    #pragma unroll
    for (int q = 0; q < 8; ++q) {
        float4 a = yi[q], b = yj[q];
        float dx = a.x - b.x, dy = a.y - b.y, dz = a.z - b.z, dw = a.w - b.w;
        s += dx * dx + dy * dy + dz * dz + dw * dw;
    }
    double local = (double)s * ((double)d2[i] + (double)d2[j]);
    #pragma unroll
    for (int off = 32; off > 0; off >>= 1) local += __shfl_down(local, off);
    __shared__ double wsum[4];
    if ((threadIdx.x & 63) == 0) wsum[threadIdx.x >> 6] = local;
    __syncthreads();
    if (threadIdx.x == 0)
        part[blockIdx.x] = wsum[0] + wsum[1] + wsum[2] + wsum[3];
}

__global__ __launch_bounds__(256) void reduce_part_k(
    const double* __restrict__ part, int n, float* __restrict__ out) {
    double s = 0.0;
    for (int i = threadIdx.x; i < n; i += 256) s += part[i];
    #pragma unroll
    for (int off = 32; off > 0; off >>= 1) s += __shfl_down(s, off);
    __shared__ double wsum[4];
    if ((threadIdx.x & 63) == 0) wsum[threadIdx.x >> 6] = s;
    __syncthreads();
    if (threadIdx.x == 0)
        out[0] = (float)((wsum[0] + wsum[1] + wsum[2] + wsum[3]) / (double)NPTS);
}

// ---------------------------------------------------------------------------
extern "C" void kernel_launch(void* const* d_in, const int* in_sizes, int n_in,
                              void* d_out, int out_size, void* d_ws, size_t ws_size,
                              hipStream_t stream) {
    const float* x1     = (const float*)d_in[0];
    const float* x2     = (const float*)d_in[1];
    const float* dists1 = (const float*)d_in[2];
    const int*   nn1    = (const int*)  d_in[3];
    const float* dists2 = (const float*)d_in[4];
    const int*   nn2    = (const int*)  d_in[5];
    const float* W1 = (const float*)d_in[6];  const float* b1 = (const float*)d_in[7];
    const float* W2 = (const float*)d_in[8];  const float* b2 = (const float*)d_in[9];
    const float* W3 = (const float*)d_in[10]; const float* b3 = (const float*)d_in[11];
    const float* W4 = (const float*)d_in[12]; const float* b4 = (const float*)d_in[13];

    char* ws = (char*)d_ws;
    size_t off = 0;
    auto alloc = [&](size_t bytes) { char* p = ws + off; off += (bytes + 255) & ~(size_t)255; return p; };
    u16*    xb   = (u16*)   alloc((size_t)NPTS * INDIM * 2);
    float*  yraw = (float*) alloc((size_t)NPTS * ODIM * 4);
    float*  yop  = (float*) alloc((size_t)NPTS * ODIM * 4);
    u16*    W1t  = (u16*)   alloc((size_t)HID * INDIM * 2);
    u16*    W2t  = (u16*)   alloc((size_t)HID * HID * 2);
    u16*    W3t  = (u16*)   alloc((size_t)HID2 * HID * 2);
    u16*    W4t  = (u16*)   alloc((size_t)ODIM * HID2 * 2);
    float*  d1   = (float*) alloc((size_t)NPTS * 4);
    float*  d2   = (float*) alloc((size_t)NPTS * 4);
    float*  gram = (float*) alloc(32 * 32 * 4);
    float*  oper = (float*) alloc(32 * 32 * 4);
    double* part = (double*)alloc((size_t)(NPTS * KNN / 256) * 8);
    size_t fixed = off;
    (void)in_sizes; (void)n_in; (void)out_size;

    // Chunk the MLP so 2 x chunk x 1024 bf16 activation buffers fit ws_size.
    int chunk = 2048;
    for (int c = NPTS; c >= 2048; c >>= 1)
        if (fixed + (size_t)c * 1024 * 2 * 2 + 512 <= ws_size) { chunk = c; break; }
    u16* cb1 = (u16*)alloc((size_t)chunk * HID * 2);
    u16* cb2 = (u16*)alloc((size_t)chunk * HID * 2);

    // weight transposes + zero-init
    trans_bf16_k<<<(INDIM * HID + 255) / 256, 256, 0, stream>>>(W1, W1t, INDIM, HID);
    trans_bf16_k<<<(HID * HID + 255) / 256, 256, 0, stream>>>(W2, W2t, HID, HID);
    trans_bf16_k<<<(HID * HID2 + 255) / 256, 256, 0, stream>>>(W3, W3t, HID, HID2);
    trans_bf16_k<<<(HID2 * ODIM + 255) / 256, 256, 0, stream>>>(W4, W4t, HID2, ODIM);
    hipMemsetAsync(d1, 0, (size_t)NPTS * 4, stream);
    hipMemsetAsync(d2, 0, (size_t)NPTS * 4, stream);
    hipMemsetAsync(gram, 0, 32 * 32 * 4, stream);

    degree_k<<<NPTS / 256, 256, 0, stream>>>(dists1, nn1, d1);
    degree_k<<<NPTS / 256, 256, 0, stream>>>(dists2, nn2, d2);

    dim3 gL12(HID / 128, chunk / 128), gL3(HID2 / 128, chunk / 128);

    for (int pass = 0; pass < 2; ++pass) {
        const float* x = pass == 0 ? x1 : x2;
        cvt_bf16_k<<<(NPTS * INDIM / 4 + 255) / 256, 256, 0, stream>>>(x, xb, NPTS * INDIM / 4);
        for (int s0 = 0; s0 < NPTS; s0 += chunk) {
            const u16* Ain = xb + (size_t)s0 * INDIM;
            gemm_bt_k<true><<<gL12, 256, 0, stream>>>(Ain, W1t, b1, cb1, chunk, HID, INDIM);
            gemm_bt_k<true><<<gL12, 256, 0, stream>>>(cb1, W2t, b2, cb2, chunk, HID, HID);
            gemm_bt_k<true><<<gL3, 256, 0, stream>>>(cb2, W3t, b3, cb1, chunk, HID2, HID);
            layer4_k<<<chunk / 64, 256, 0, stream>>>(
                cb1, W4t, b4, pass == 0 ? d1 + s0 : nullptr,
                yraw + (size_t)s0 * ODIM, chunk);
        }
        if (pass == 0) {
            gram_k<<<256, 256, 0, stream>>>(yraw, gram);
            chol_oper_k<<<1, 64, 0, stream>>>(gram, oper);
        } else {
            apply_oper_k<<<NPTS * ODIM / 256, 256, 0, stream>>>(yraw, oper, d2, yop);
            loss_k<<<NPTS * KNN / 256, 256, 0, stream>>>(yop, nn2, d2, part);
            reduce_part_k<<<1, 256, 0, stream>>>(part, NPTS * KNN / 256, (float*)d_out);
        }
    }
}